// Round 7
// baseline (749.142 us; speedup 1.0000x reference)
//
#include <hip/hip_runtime.h>
#include <hip/hip_bf16.h>

// FourierBlock: B=16, L=4096, H=3, E=512, M=128 modes.
// Pipeline:
//   1. build_ta: T_A[m2=256][l=4096] bf16  (cos / -sin interleaved)
//   2. build_tc: T_C[l=4096][m2=256] bf16  (irfft scale c_m/L folded in HERE ONLY)
//   3. gemm_a  : Xbf[h,b,i,m2] bf16 = q[b,:,ch] . T_A^T  (fused f32 load +
//                transpose + cast + MFMA, K=4096; q read exactly once)
//   4. stage_b : Ybf[(b,h,o)][m2] bf16 = complex channel mix
//                (fp32 VALU, 2-deep weight prefetch, X direct from L2)
//   5. gemm<1> : out[(b,h,o)][l] f32 = Ybf . T_C^T        (MFMA bf16, K=256)
//
// ws: Xbf bf16 12,582,912 B @0 | Ybf bf16 12,582,912 B @25165824
//     T_A bf16 2,097,152 B @37748736 | T_C bf16 2,097,152 B @39845888

#define L_TOT 4096

typedef __attribute__((ext_vector_type(4))) float f32x4;
typedef __attribute__((ext_vector_type(4))) unsigned u32x4;
typedef __attribute__((ext_vector_type(8))) short s16x8;
typedef __attribute__((ext_vector_type(4))) unsigned short u16x4;

__device__ __forceinline__ unsigned short f2bf(float f) {
    unsigned u = __builtin_bit_cast(unsigned, f);
    u = (u + 0x7fffu + ((u >> 16) & 1u)) >> 16;
    return (unsigned short)u;
}

__device__ __forceinline__ void gload_lds16(const void* g, void* l) {
    __builtin_amdgcn_global_load_lds((const __attribute__((address_space(1))) void*)g,
                                     (__attribute__((address_space(3))) void*)l,
                                     16, 0, 0);
}

__global__ __launch_bounds__(256) void build_ta(const int* __restrict__ index,
                                                unsigned short* __restrict__ T_A) {
    const int idx = blockIdx.x * 256 + threadIdx.x;
    const int m2 = idx >> 12;
    const int l  = idx & (L_TOT - 1);
    const int k  = index[m2 >> 1];
    const int tt = (k * l) & (L_TOT - 1);
    const float x = (float)tt * (1.0f / 2048.0f);
    T_A[idx] = f2bf((m2 & 1) ? -sinpif(x) : cospif(x));
}

__global__ __launch_bounds__(256) void build_tc(const int* __restrict__ index,
                                                unsigned short* __restrict__ T_C) {
    const int idx = blockIdx.x * 256 + threadIdx.x;
    const int l  = idx >> 8;
    const int m2 = idx & 255;
    const int k  = index[m2 >> 1];
    const int tt = (k * l) & (L_TOT - 1);
    const float x = (float)tt * (1.0f / 2048.0f);
    const float s = (k == 0 ? 1.0f : 2.0f) * (1.0f / (float)L_TOT);
    T_C[idx] = f2bf(s * ((m2 & 1) ? -sinpif(x) : cospif(x)));
}

// ---- gemm_a: fused transpose+cast+GEMM (stage A of the DFT) ----
// grid 384 = b(16) x cht(24); block 256 = 4 waves.
// BM=64 (ch rows), BN=256 (all m2), BK=64 (l).
// A staged from q f32 via in-register 4x4 transpose + f2bf + swizzled ds_write.
// B (T_A) staged via global_load_lds with pre-swizzled source (as before).
__global__ __launch_bounds__(256) void gemm_a(const float* __restrict__ q,
                                              const unsigned short* __restrict__ T_A,
                                              unsigned short* __restrict__ Xbf) {
    __shared__ unsigned short As[64 * 64];    // [ch][l^swz]  8 KB
    __shared__ unsigned short Bs[256 * 64];   // [m2][l^swz] 32 KB

    const int bid = blockIdx.x;
    const int b   = bid / 24;
    const int cht = bid % 24;
    const int ch0 = cht * 64;
    const int h   = ch0 >> 9;
    const int i0  = ch0 & 511;
    const int t   = threadIdx.x;
    const int lane = t & 63;
    const int w    = t >> 6;
    const int chq  = t & 15;     // 16 lanes cover 64 ch as float4
    const int lg   = t >> 4;     // 16 groups cover 64 l as 4-l strips

    const float* qb = q + (size_t)b * L_TOT * 1536 + ch0 + chq * 4;

    f32x4 acc[4][4];
#pragma unroll
    for (int mi = 0; mi < 4; ++mi)
#pragma unroll
        for (int ni = 0; ni < 4; ++ni) acc[mi][ni] = (f32x4)0.0f;

    for (int kt = 0; kt < L_TOT; kt += 64) {
        __syncthreads();
        // B tile: 256 rows x 64 l, pre-swizzled global source, linear LDS dest
#pragma unroll
        for (int p = 0; p < 8; ++p) {
            const int u = p * 256 + t;
            const int row = u >> 3, c16 = u & 7;
            const unsigned short* src = T_A + (size_t)row * L_TOT + kt + ((c16 ^ (row & 7)) * 8);
            unsigned short* dst = Bs + (size_t)(p * 256 + w * 64) * 8;
            gload_lds16(src, dst);
        }
        // A tile: load q [4 l][4 ch] f32, transpose in registers, swizzled write
        f32x4 v[4];
#pragma unroll
        for (int r = 0; r < 4; ++r)
            v[r] = *reinterpret_cast<const f32x4*>(qb + (size_t)(kt + lg * 4 + r) * 1536);
#pragma unroll
        for (int j = 0; j < 4; ++j) {
            const int c = chq * 4 + j;
            uint2 pk;
            pk.x = f2bf(v[0][j]) | ((unsigned)f2bf(v[1][j]) << 16);
            pk.y = f2bf(v[2][j]) | ((unsigned)f2bf(v[3][j]) << 16);
            *reinterpret_cast<uint2*>(As + c * 64 + ((lg * 4) ^ ((c & 7) << 3))) = pk;
        }
        __syncthreads();

#pragma unroll
        for (int kk = 0; kk < 2; ++kk) {
            const int c16 = kk * 4 + (lane >> 4);
            s16x8 af[4], bfr[4];
#pragma unroll
            for (int mi = 0; mi < 4; ++mi) {
                const int row = mi * 16 + (lane & 15);
                af[mi] = *reinterpret_cast<const s16x8*>(As + row * 64 + ((c16 ^ (row & 7)) * 8));
            }
#pragma unroll
            for (int ni = 0; ni < 4; ++ni) {
                const int row = w * 64 + ni * 16 + (lane & 15);
                bfr[ni] = *reinterpret_cast<const s16x8*>(Bs + row * 64 + ((c16 ^ (row & 7)) * 8));
            }
#pragma unroll
            for (int mi = 0; mi < 4; ++mi)
#pragma unroll
                for (int ni = 0; ni < 4; ++ni)
                    acc[mi][ni] = __builtin_amdgcn_mfma_f32_16x16x32_bf16(af[mi], bfr[ni], acc[mi][ni], 0, 0, 0);
        }
    }

    // epilogue: Xbf[h][b][i0+row][col] bf16
    const size_t cbase = (((size_t)h * 16 + b) * 512 + i0) * 256;
#pragma unroll
    for (int mi = 0; mi < 4; ++mi) {
        const int r0 = mi * 16 + (lane >> 4) * 4;
#pragma unroll
        for (int ni = 0; ni < 4; ++ni) {
            const int col = w * 64 + ni * 16 + (lane & 15);
#pragma unroll
            for (int j = 0; j < 4; ++j)
                Xbf[cbase + (size_t)(r0 + j) * 256 + col] = f2bf(acc[mi][ni][j]);
        }
    }
}

// ---- MFMA GEMM (stage C): out[(b,h,o)][l] f32 = Ybf . T_C^T ----
template <int MODE>
__global__ __launch_bounds__(256) void gemm_bf16(const unsigned short* __restrict__ A,
                                                 const unsigned short* __restrict__ Bt,
                                                 void* __restrict__ Cv) {
    constexpr int BM   = 128;
    constexpr int BK   = 64;
    constexpr int KTOT = 256;
    constexpr int LDAB = 256;
    constexpr int LDC  = 4096;
    constexpr int MFR  = BM / 32;
    constexpr int APASS = BM * 8 / 256;
    constexpr int BPASS = 4;

    __shared__ unsigned short As[BM * BK];
    __shared__ unsigned short Bs[128 * BK];

    const int t = threadIdx.x;
    const int lane = t & 63;
    const int w = t >> 6;
    const int wr = w >> 1, wc = w & 1;

    const int mt = blockIdx.x >> 5, nt = blockIdx.x & 31;
    const unsigned short* Ab = A + (size_t)mt * 128 * 256;
    const unsigned short* Bb = Bt + (size_t)nt * 128 * 256;
    const size_t cbase = (size_t)mt * 128 * 4096 + nt * 128;

    f32x4 acc[MFR][4];
#pragma unroll
    for (int mi = 0; mi < MFR; ++mi)
#pragma unroll
        for (int ni = 0; ni < 4; ++ni) acc[mi][ni] = (f32x4)0.0f;

    for (int kt = 0; kt < KTOT; kt += BK) {
        __syncthreads();
#pragma unroll
        for (int p = 0; p < APASS; ++p) {
            const int u = p * 256 + t;
            const int row = u >> 3, c16 = u & 7;
            const unsigned short* src = Ab + (size_t)row * LDAB + kt + ((c16 ^ (row & 7)) * 8);
            unsigned short* dst = As + (size_t)(p * 256 + w * 64) * 8;
            gload_lds16(src, dst);
        }
#pragma unroll
        for (int p = 0; p < BPASS; ++p) {
            const int u = p * 256 + t;
            const int row = u >> 3, c16 = u & 7;
            const unsigned short* src = Bb + (size_t)row * LDAB + kt + ((c16 ^ (row & 7)) * 8);
            unsigned short* dst = Bs + (size_t)(p * 256 + w * 64) * 8;
            gload_lds16(src, dst);
        }
        __syncthreads();

#pragma unroll
        for (int kk = 0; kk < 2; ++kk) {
            const int c16 = kk * 4 + (lane >> 4);
            s16x8 af[MFR], bfr[4];
#pragma unroll
            for (int mi = 0; mi < MFR; ++mi) {
                const int row = wr * (BM / 2) + mi * 16 + (lane & 15);
                af[mi] = *reinterpret_cast<const s16x8*>(As + row * BK + ((c16 ^ (row & 7)) * 8));
            }
#pragma unroll
            for (int ni = 0; ni < 4; ++ni) {
                const int row = wc * 64 + ni * 16 + (lane & 15);
                bfr[ni] = *reinterpret_cast<const s16x8*>(Bs + row * BK + ((c16 ^ (row & 7)) * 8));
            }
#pragma unroll
            for (int mi = 0; mi < MFR; ++mi)
#pragma unroll
                for (int ni = 0; ni < 4; ++ni)
                    acc[mi][ni] = __builtin_amdgcn_mfma_f32_16x16x32_bf16(af[mi], bfr[ni], acc[mi][ni], 0, 0, 0);
        }
    }

#pragma unroll
    for (int mi = 0; mi < MFR; ++mi) {
        const int r0 = wr * (BM / 2) + mi * 16 + (lane >> 4) * 4;
#pragma unroll
        for (int ni = 0; ni < 4; ++ni) {
            const int col = wc * 64 + ni * 16 + (lane & 15);
#pragma unroll
            for (int j = 0; j < 4; ++j)
                ((float*)Cv)[cbase + (size_t)(r0 + j) * LDC + col] = acc[mi][ni][j];
        }
    }
}

// ---- Stage B v4: barrier-free, 2-deep weight prefetch ----
// grid 768: bid = bq*192 + h*64 + ot; block 256 = 4 waves
// wave w: o = ot*8 + w*2 + {0,1}; lane: m4 = lane&31, h1 = lane>>5
// b = bq*4 + h1*2 + {0,1}.  Per 2-i sub-body: issue 4 X uint4 (L2) first,
// then next sub-body's 8 W float4 (HBM), then 128 FMA — FMAs wait only on X
// (vmcnt(8)), W prefetch stays in flight across the FMA block.
#define SB_LDX(XV, I0)                                                   \
    _Pragma("unroll")                                                    \
    for (int s = 0; s < 2; ++s) {                                        \
        const size_t xo = (size_t)((I0) + s) * 256;                      \
        XV[s][0] = *reinterpret_cast<const u32x4*>(x0 + xo);             \
        XV[s][1] = *reinterpret_cast<const u32x4*>(x0 + 131072 + xo);    \
    }

#define SB_PREF(WRD, WID, I0)                                            \
    _Pragma("unroll")                                                    \
    for (int s = 0; s < 2; ++s) {                                        \
        const size_t io = (size_t)(((I0) + s) & 511) * 65536;            \
        WRD[s][0] = *reinterpret_cast<const f32x4*>(wrp + io);           \
        WRD[s][1] = *reinterpret_cast<const f32x4*>(wrp + io + 128);     \
        WID[s][0] = *reinterpret_cast<const f32x4*>(wip + io);           \
        WID[s][1] = *reinterpret_cast<const f32x4*>(wip + io + 128);     \
    }

#define SB_FMA(XV, WRV, WIV)                                             \
    _Pragma("unroll")                                                    \
    for (int s = 0; s < 2; ++s)                                          \
    _Pragma("unroll")                                                    \
    for (int bb = 0; bb < 2; ++bb) {                                     \
        _Pragma("unroll")                                                \
        for (int j = 0; j < 4; ++j) {                                    \
            const unsigned xu = XV[s][bb][j];                            \
            const float xr = __builtin_bit_cast(float, xu << 16);        \
            const float xi = __builtin_bit_cast(float, xu & 0xffff0000u);\
            _Pragma("unroll")                                            \
            for (int oo = 0; oo < 2; ++oo) {                             \
                const float wrj = WRV[s][oo][j];                         \
                const float wij = WIV[s][oo][j];                         \
                aR[bb][oo][j] = fmaf(xr, wrj, aR[bb][oo][j]);            \
                aR[bb][oo][j] = fmaf(-xi, wij, aR[bb][oo][j]);           \
                aI[bb][oo][j] = fmaf(xr, wij, aI[bb][oo][j]);            \
                aI[bb][oo][j] = fmaf(xi, wrj, aI[bb][oo][j]);            \
            }                                                            \
        }                                                                \
    }

__global__ __launch_bounds__(256, 3) void stage_b(const unsigned short* __restrict__ Xbf,
                                                  const float* __restrict__ wr,
                                                  const float* __restrict__ wi,
                                                  unsigned short* __restrict__ Ybf) {
    const int bid = blockIdx.x;
    const int ot  = bid & 63;
    const int tmp = bid >> 6;          // = bq*3 + h
    const int h   = tmp % 3;
    const int bq  = tmp / 3;
    const int t    = threadIdx.x;
    const int lane = t & 63;
    const int w    = t >> 6;
    const int m4   = lane & 31;
    const int h1   = lane >> 5;
    const int b0   = bq * 4 + h1 * 2;          // b0, b0+1
    const int o    = ot * 8 + w * 2;           // o, o+1

    const size_t wbase = (size_t)h * 33554432 + (size_t)o * 128 + m4 * 4;
    const float* wrp = wr + wbase;
    const float* wip = wi + wbase;
    const unsigned short* x0 = Xbf + (size_t)(h * 16 + b0) * 512 * 256 + m4 * 8;

    float aR[2][2][4], aI[2][2][4];            // [b][o][m]
#pragma unroll
    for (int bb = 0; bb < 2; ++bb)
#pragma unroll
        for (int oo = 0; oo < 2; ++oo)
#pragma unroll
            for (int j = 0; j < 4; ++j) { aR[bb][oo][j] = 0.f; aI[bb][oo][j] = 0.f; }

    f32x4 wrA[2][2], wiA[2][2], wrB[2][2], wiB[2][2];
    SB_PREF(wrA, wiA, 0);

#pragma unroll 1
    for (int i = 0; i < 512; i += 4) {
        {
            u32x4 xv[2][2];
            SB_LDX(xv, i);
            SB_PREF(wrB, wiB, i + 2);
            SB_FMA(xv, wrA, wiA);
        }
        {
            u32x4 xv[2][2];
            SB_LDX(xv, i + 2);
            SB_PREF(wrA, wiA, i + 4);
            SB_FMA(xv, wrB, wiB);
        }
    }

#pragma unroll
    for (int bb = 0; bb < 2; ++bb)
#pragma unroll
        for (int oo = 0; oo < 2; ++oo) {
            const size_t row = ((size_t)(b0 + bb) * 3 + h) * 512 + o + oo;
            uint4 pk;
            pk.x = f2bf(aR[bb][oo][0]) | ((unsigned)f2bf(aI[bb][oo][0]) << 16);
            pk.y = f2bf(aR[bb][oo][1]) | ((unsigned)f2bf(aI[bb][oo][1]) << 16);
            pk.z = f2bf(aR[bb][oo][2]) | ((unsigned)f2bf(aI[bb][oo][2]) << 16);
            pk.w = f2bf(aR[bb][oo][3]) | ((unsigned)f2bf(aI[bb][oo][3]) << 16);
            *reinterpret_cast<uint4*>(reinterpret_cast<char*>(Ybf) + row * 512 + m4 * 16) = pk;
        }
}

extern "C" void kernel_launch(void* const* d_in, const int* in_sizes, int n_in,
                              void* d_out, int out_size, void* d_ws, size_t ws_size,
                              hipStream_t stream) {
    const float* q     = (const float*)d_in[0];
    const float* w_re  = (const float*)d_in[1];
    const float* w_im  = (const float*)d_in[2];
    const int*   index = (const int*)d_in[3];

    char* ws = (char*)d_ws;
    unsigned short* Xbf = (unsigned short*)(ws);                // 12,582,912 B
    unsigned short* Ybf = (unsigned short*)(ws + 25165824);     // 12,582,912 B
    unsigned short* T_A = (unsigned short*)(ws + 37748736);
    unsigned short* T_C = (unsigned short*)(ws + 39845888);

    build_ta<<<4096, 256, 0, stream>>>(index, T_A);
    build_tc<<<4096, 256, 0, stream>>>(index, T_C);
    gemm_a<<<384, 256, 0, stream>>>(q, T_A, Xbf);
    stage_b<<<768, 256, 0, stream>>>(Xbf, w_re, w_im, Ybf);
    gemm_bf16<1><<<6144, 256, 0, stream>>>(Ybf, T_C, (void*)d_out);
}

// Round 8
// 713.083 us; speedup vs baseline: 1.0506x; 1.0506x over previous
//
#include <hip/hip_runtime.h>
#include <hip/hip_bf16.h>

// FourierBlock: B=16, L=4096, H=3, E=512, M=128 modes.
// Pipeline:
//   1. build_ta: T_A[m2=256][l=4096] bf16  (cos / -sin interleaved)
//   2. build_tc: T_C[l=4096][m2=256] bf16  (irfft scale c_m/L folded in HERE ONLY)
//   3. gemm_a  : Xbf[h,b,i,m2] bf16 = q[b,:,ch] . T_A^T  (fused f32 load +
//                transpose + cast + MFMA, K=4096; q read exactly once)
//   4. stage_b : Ybf[(b,h,o)][m2] bf16 = complex channel mix
//                (fp32 VALU, r6-style load/drain/FMA bodies, 4 i per body)
//   5. gemm<1> : out[(b,h,o)][l] f32 = Ybf . T_C^T        (MFMA bf16, K=256)
//
// ws: Xbf bf16 12,582,912 B @0 | Ybf bf16 12,582,912 B @25165824
//     T_A bf16 2,097,152 B @37748736 | T_C bf16 2,097,152 B @39845888

#define L_TOT 4096

typedef __attribute__((ext_vector_type(4))) float f32x4;
typedef __attribute__((ext_vector_type(4))) unsigned u32x4;
typedef __attribute__((ext_vector_type(8))) short s16x8;
typedef __attribute__((ext_vector_type(4))) unsigned short u16x4;

__device__ __forceinline__ unsigned short f2bf(float f) {
    unsigned u = __builtin_bit_cast(unsigned, f);
    u = (u + 0x7fffu + ((u >> 16) & 1u)) >> 16;
    return (unsigned short)u;
}

__device__ __forceinline__ void gload_lds16(const void* g, void* l) {
    __builtin_amdgcn_global_load_lds((const __attribute__((address_space(1))) void*)g,
                                     (__attribute__((address_space(3))) void*)l,
                                     16, 0, 0);
}

__global__ __launch_bounds__(256) void build_ta(const int* __restrict__ index,
                                                unsigned short* __restrict__ T_A) {
    const int idx = blockIdx.x * 256 + threadIdx.x;
    const int m2 = idx >> 12;
    const int l  = idx & (L_TOT - 1);
    const int k  = index[m2 >> 1];
    const int tt = (k * l) & (L_TOT - 1);
    const float x = (float)tt * (1.0f / 2048.0f);
    T_A[idx] = f2bf((m2 & 1) ? -sinpif(x) : cospif(x));
}

__global__ __launch_bounds__(256) void build_tc(const int* __restrict__ index,
                                                unsigned short* __restrict__ T_C) {
    const int idx = blockIdx.x * 256 + threadIdx.x;
    const int l  = idx >> 8;
    const int m2 = idx & 255;
    const int k  = index[m2 >> 1];
    const int tt = (k * l) & (L_TOT - 1);
    const float x = (float)tt * (1.0f / 2048.0f);
    const float s = (k == 0 ? 1.0f : 2.0f) * (1.0f / (float)L_TOT);
    T_C[idx] = f2bf(s * ((m2 & 1) ? -sinpif(x) : cospif(x)));
}

// ---- gemm_a: fused transpose+cast+GEMM (stage A of the DFT) ----
// grid 384 = b(16) x cht(24); block 256 = 4 waves.
// BM=64 (ch rows), BN=256 (all m2), BK=64 (l).
__global__ __launch_bounds__(256) void gemm_a(const float* __restrict__ q,
                                              const unsigned short* __restrict__ T_A,
                                              unsigned short* __restrict__ Xbf) {
    __shared__ unsigned short As[64 * 64];    // [ch][l^swz]  8 KB
    __shared__ unsigned short Bs[256 * 64];   // [m2][l^swz] 32 KB

    const int bid = blockIdx.x;
    const int b   = bid / 24;
    const int cht = bid % 24;
    const int ch0 = cht * 64;
    const int h   = ch0 >> 9;
    const int i0  = ch0 & 511;
    const int t   = threadIdx.x;
    const int lane = t & 63;
    const int w    = t >> 6;
    const int chq  = t & 15;
    const int lg   = t >> 4;

    const float* qb = q + (size_t)b * L_TOT * 1536 + ch0 + chq * 4;

    f32x4 acc[4][4];
#pragma unroll
    for (int mi = 0; mi < 4; ++mi)
#pragma unroll
        for (int ni = 0; ni < 4; ++ni) acc[mi][ni] = (f32x4)0.0f;

    for (int kt = 0; kt < L_TOT; kt += 64) {
        __syncthreads();
#pragma unroll
        for (int p = 0; p < 8; ++p) {
            const int u = p * 256 + t;
            const int row = u >> 3, c16 = u & 7;
            const unsigned short* src = T_A + (size_t)row * L_TOT + kt + ((c16 ^ (row & 7)) * 8);
            unsigned short* dst = Bs + (size_t)(p * 256 + w * 64) * 8;
            gload_lds16(src, dst);
        }
        f32x4 v[4];
#pragma unroll
        for (int r = 0; r < 4; ++r)
            v[r] = *reinterpret_cast<const f32x4*>(qb + (size_t)(kt + lg * 4 + r) * 1536);
#pragma unroll
        for (int j = 0; j < 4; ++j) {
            const int c = chq * 4 + j;
            uint2 pk;
            pk.x = f2bf(v[0][j]) | ((unsigned)f2bf(v[1][j]) << 16);
            pk.y = f2bf(v[2][j]) | ((unsigned)f2bf(v[3][j]) << 16);
            *reinterpret_cast<uint2*>(As + c * 64 + ((lg * 4) ^ ((c & 7) << 3))) = pk;
        }
        __syncthreads();

#pragma unroll
        for (int kk = 0; kk < 2; ++kk) {
            const int c16 = kk * 4 + (lane >> 4);
            s16x8 af[4], bfr[4];
#pragma unroll
            for (int mi = 0; mi < 4; ++mi) {
                const int row = mi * 16 + (lane & 15);
                af[mi] = *reinterpret_cast<const s16x8*>(As + row * 64 + ((c16 ^ (row & 7)) * 8));
            }
#pragma unroll
            for (int ni = 0; ni < 4; ++ni) {
                const int row = w * 64 + ni * 16 + (lane & 15);
                bfr[ni] = *reinterpret_cast<const s16x8*>(Bs + row * 64 + ((c16 ^ (row & 7)) * 8));
            }
#pragma unroll
            for (int mi = 0; mi < 4; ++mi)
#pragma unroll
                for (int ni = 0; ni < 4; ++ni)
                    acc[mi][ni] = __builtin_amdgcn_mfma_f32_16x16x32_bf16(af[mi], bfr[ni], acc[mi][ni], 0, 0, 0);
        }
    }

    const size_t cbase = (((size_t)h * 16 + b) * 512 + i0) * 256;
#pragma unroll
    for (int mi = 0; mi < 4; ++mi) {
        const int r0 = mi * 16 + (lane >> 4) * 4;
#pragma unroll
        for (int ni = 0; ni < 4; ++ni) {
            const int col = w * 64 + ni * 16 + (lane & 15);
#pragma unroll
            for (int j = 0; j < 4; ++j)
                Xbf[cbase + (size_t)(r0 + j) * 256 + col] = f2bf(acc[mi][ni][j]);
        }
    }
}

// ---- MFMA GEMM (stage C): out[(b,h,o)][l] f32 = Ybf . T_C^T ----
template <int MODE>
__global__ __launch_bounds__(256) void gemm_bf16(const unsigned short* __restrict__ A,
                                                 const unsigned short* __restrict__ Bt,
                                                 void* __restrict__ Cv) {
    constexpr int BM   = 128;
    constexpr int BK   = 64;
    constexpr int KTOT = 256;
    constexpr int LDAB = 256;
    constexpr int LDC  = 4096;
    constexpr int MFR  = BM / 32;
    constexpr int APASS = BM * 8 / 256;
    constexpr int BPASS = 4;

    __shared__ unsigned short As[BM * BK];
    __shared__ unsigned short Bs[128 * BK];

    const int t = threadIdx.x;
    const int lane = t & 63;
    const int w = t >> 6;
    const int wr = w >> 1, wc = w & 1;

    const int mt = blockIdx.x >> 5, nt = blockIdx.x & 31;
    const unsigned short* Ab = A + (size_t)mt * 128 * 256;
    const unsigned short* Bb = Bt + (size_t)nt * 128 * 256;
    const size_t cbase = (size_t)mt * 128 * 4096 + nt * 128;

    f32x4 acc[MFR][4];
#pragma unroll
    for (int mi = 0; mi < MFR; ++mi)
#pragma unroll
        for (int ni = 0; ni < 4; ++ni) acc[mi][ni] = (f32x4)0.0f;

    for (int kt = 0; kt < KTOT; kt += BK) {
        __syncthreads();
#pragma unroll
        for (int p = 0; p < APASS; ++p) {
            const int u = p * 256 + t;
            const int row = u >> 3, c16 = u & 7;
            const unsigned short* src = Ab + (size_t)row * LDAB + kt + ((c16 ^ (row & 7)) * 8);
            unsigned short* dst = As + (size_t)(p * 256 + w * 64) * 8;
            gload_lds16(src, dst);
        }
#pragma unroll
        for (int p = 0; p < BPASS; ++p) {
            const int u = p * 256 + t;
            const int row = u >> 3, c16 = u & 7;
            const unsigned short* src = Bb + (size_t)row * LDAB + kt + ((c16 ^ (row & 7)) * 8);
            unsigned short* dst = Bs + (size_t)(p * 256 + w * 64) * 8;
            gload_lds16(src, dst);
        }
        __syncthreads();

#pragma unroll
        for (int kk = 0; kk < 2; ++kk) {
            const int c16 = kk * 4 + (lane >> 4);
            s16x8 af[MFR], bfr[4];
#pragma unroll
            for (int mi = 0; mi < MFR; ++mi) {
                const int row = wr * (BM / 2) + mi * 16 + (lane & 15);
                af[mi] = *reinterpret_cast<const s16x8*>(As + row * BK + ((c16 ^ (row & 7)) * 8));
            }
#pragma unroll
            for (int ni = 0; ni < 4; ++ni) {
                const int row = wc * 64 + ni * 16 + (lane & 15);
                bfr[ni] = *reinterpret_cast<const s16x8*>(Bs + row * BK + ((c16 ^ (row & 7)) * 8));
            }
#pragma unroll
            for (int mi = 0; mi < MFR; ++mi)
#pragma unroll
                for (int ni = 0; ni < 4; ++ni)
                    acc[mi][ni] = __builtin_amdgcn_mfma_f32_16x16x32_bf16(af[mi], bfr[ni], acc[mi][ni], 0, 0, 0);
        }
    }

#pragma unroll
    for (int mi = 0; mi < MFR; ++mi) {
        const int r0 = wr * (BM / 2) + mi * 16 + (lane >> 4) * 4;
#pragma unroll
        for (int ni = 0; ni < 4; ++ni) {
            const int col = wc * 64 + ni * 16 + (lane & 15);
#pragma unroll
            for (int j = 0; j < 4; ++j)
                ((float*)Cv)[cbase + (size_t)(r0 + j) * LDC + col] = acc[mi][ni][j];
        }
    }
}

// ---- Stage B v5: r6 structure, 4-i bodies (24 loads in flight per drain) ----
// grid 768: bid = bq*192 + h*64 + ot; block 256 = 4 waves
// wave w: o = ot*8 + w*2 + {0,1}; lane: m4 = lane&31, h1 = lane>>5
// b = bq*4 + h1*2 + {0,1}.  Per 4-i body: 16 W float4 (HBM) + 8 X uint4 (L2)
// issued up front, one drain, 256 FMA. No LDS, no barriers, no manual prefetch.
__global__ __launch_bounds__(256, 3) void stage_b(const unsigned short* __restrict__ Xbf,
                                                  const float* __restrict__ wr,
                                                  const float* __restrict__ wi,
                                                  unsigned short* __restrict__ Ybf) {
    const int bid = blockIdx.x;
    const int ot  = bid & 63;
    const int tmp = bid >> 6;          // = bq*3 + h
    const int h   = tmp % 3;
    const int bq  = tmp / 3;
    const int t    = threadIdx.x;
    const int lane = t & 63;
    const int w    = t >> 6;
    const int m4   = lane & 31;
    const int h1   = lane >> 5;
    const int b0   = bq * 4 + h1 * 2;          // b0, b0+1
    const int o    = ot * 8 + w * 2;           // o, o+1

    const size_t wbase = (size_t)h * 33554432 + (size_t)o * 128 + m4 * 4;
    const float* wrp = wr + wbase;             // + i*65536; o+1 -> +128
    const float* wip = wi + wbase;
    const unsigned short* x0 = Xbf + (size_t)(h * 16 + b0) * 512 * 256 + m4 * 8;  // + i*256; b+1 -> +131072

    float aR[2][2][4], aI[2][2][4];            // [b][o][m]
#pragma unroll
    for (int bb = 0; bb < 2; ++bb)
#pragma unroll
        for (int oo = 0; oo < 2; ++oo)
#pragma unroll
            for (int j = 0; j < 4; ++j) { aR[bb][oo][j] = 0.f; aI[bb][oo][j] = 0.f; }

#pragma unroll 1
    for (int i = 0; i < 512; i += 4) {
        // issue all 24 loads first: weights (HBM) then X (L2-resident)
        f32x4 wrv[4][2], wiv[4][2];            // [istep][o]
        u32x4 xv[4][2];                        // [istep][b]
#pragma unroll
        for (int s = 0; s < 4; ++s) {
            const size_t io = (size_t)(i + s) * 65536;
            wrv[s][0] = *reinterpret_cast<const f32x4*>(wrp + io);
            wrv[s][1] = *reinterpret_cast<const f32x4*>(wrp + io + 128);
            wiv[s][0] = *reinterpret_cast<const f32x4*>(wip + io);
            wiv[s][1] = *reinterpret_cast<const f32x4*>(wip + io + 128);
        }
#pragma unroll
        for (int s = 0; s < 4; ++s) {
            const size_t xo = (size_t)(i + s) * 256;
            xv[s][0] = *reinterpret_cast<const u32x4*>(x0 + xo);
            xv[s][1] = *reinterpret_cast<const u32x4*>(x0 + 131072 + xo);
        }
#pragma unroll
        for (int s = 0; s < 4; ++s)
#pragma unroll
            for (int bb = 0; bb < 2; ++bb) {
#pragma unroll
                for (int j = 0; j < 4; ++j) {
                    const unsigned xu = xv[s][bb][j];
                    const float xr = __builtin_bit_cast(float, xu << 16);
                    const float xi = __builtin_bit_cast(float, xu & 0xffff0000u);
#pragma unroll
                    for (int oo = 0; oo < 2; ++oo) {
                        const float wrj = wrv[s][oo][j];
                        const float wij = wiv[s][oo][j];
                        aR[bb][oo][j] = fmaf(xr, wrj, aR[bb][oo][j]);
                        aR[bb][oo][j] = fmaf(-xi, wij, aR[bb][oo][j]);
                        aI[bb][oo][j] = fmaf(xr, wij, aI[bb][oo][j]);
                        aI[bb][oo][j] = fmaf(xi, wrj, aI[bb][oo][j]);
                    }
                }
            }
    }

    // Ybf[(b*3+h)*512 + o][m2]: 16B vector per (b,o) at byte col m4*16
#pragma unroll
    for (int bb = 0; bb < 2; ++bb)
#pragma unroll
        for (int oo = 0; oo < 2; ++oo) {
            const size_t row = ((size_t)(b0 + bb) * 3 + h) * 512 + o + oo;
            uint4 pk;
            pk.x = f2bf(aR[bb][oo][0]) | ((unsigned)f2bf(aI[bb][oo][0]) << 16);
            pk.y = f2bf(aR[bb][oo][1]) | ((unsigned)f2bf(aI[bb][oo][1]) << 16);
            pk.z = f2bf(aR[bb][oo][2]) | ((unsigned)f2bf(aI[bb][oo][2]) << 16);
            pk.w = f2bf(aR[bb][oo][3]) | ((unsigned)f2bf(aI[bb][oo][3]) << 16);
            *reinterpret_cast<uint4*>(reinterpret_cast<char*>(Ybf) + row * 512 + m4 * 16) = pk;
        }
}

extern "C" void kernel_launch(void* const* d_in, const int* in_sizes, int n_in,
                              void* d_out, int out_size, void* d_ws, size_t ws_size,
                              hipStream_t stream) {
    const float* q     = (const float*)d_in[0];
    const float* w_re  = (const float*)d_in[1];
    const float* w_im  = (const float*)d_in[2];
    const int*   index = (const int*)d_in[3];

    char* ws = (char*)d_ws;
    unsigned short* Xbf = (unsigned short*)(ws);                // 12,582,912 B
    unsigned short* Ybf = (unsigned short*)(ws + 25165824);     // 12,582,912 B
    unsigned short* T_A = (unsigned short*)(ws + 37748736);
    unsigned short* T_C = (unsigned short*)(ws + 39845888);

    build_ta<<<4096, 256, 0, stream>>>(index, T_A);
    build_tc<<<4096, 256, 0, stream>>>(index, T_C);
    gemm_a<<<384, 256, 0, stream>>>(q, T_A, Xbf);
    stage_b<<<768, 256, 0, stream>>>(Xbf, w_re, w_im, Ybf);
    gemm_bf16<1><<<6144, 256, 0, stream>>>(Ybf, T_C, (void*)d_out);
}